// Round 8
// baseline (251.578 us; speedup 1.0000x reference)
//
#include <hip/hip_runtime.h>
#include <hip/hip_bf16.h>

// Problem constants
#define NN  50000   // nodes
#define FD  128     // features
#define NE  800000  // external edges
#define NEI 400000  // internal edges
#define NG  64      // graphs

// Workspace layout (bytes). [0, ZERO_BYTES) is zeroed each launch.
#define DEG_EXT_OFF 0        // 50000 int
#define DEG_INT_OFF 200704   // 50000 int
#define EZ_OFF      401408   // 64*128 float
#define IZ_OFF      434176   // 64*128 float
#define CNT_OFF     466944   // 64 int
#define ZERO_BYTES  467200
#define WB_OFF      467200   // 4 convs * 32768 ushort = 256 KB (B fragments)
#define WCOL_OFF    729344   // 4 * 128 float

typedef short  short8 __attribute__((ext_vector_type(8)));
typedef float  f32x4  __attribute__((ext_vector_type(4)));

union S8 { short8 s; unsigned int u[4]; };

__device__ __forceinline__ unsigned short bf16h(float f) {
  unsigned int u = __float_as_uint(f);
  u += 0x7FFFu + ((u >> 16) & 1u);            // RNE
  return (unsigned short)(u >> 16);
}
__device__ __forceinline__ float bf16tof(unsigned short h) {
  return __uint_as_float(((unsigned int)h) << 16);
}
// packed 2xf32 -> 2xbf16 (v_cvt_pk_bf16_f32): a in low 16, b in high 16
__device__ __forceinline__ unsigned int pk_bf16(float a, float b) {
  __hip_bfloat162 h = __float22bfloat162_rn(make_float2(a, b));
  unsigned int u;
  __builtin_memcpy(&u, &h, 4);
  return u;
}

// -------------------------------------------------------------------------
// ONE aux dispatch (unchanged from R7 — all pieces measured small):
//  [0,391):    ext edge-degree histogram (softmax([E,1])==1 -> counts)
//  [391,587):  int edge-degree histogram
//  [587,600):  batch histogram (sorted -> LDS-privatized)
//  [600,608):  W -> MFMA B-fragment prep (hi/lo split-bf16), LDS-staged
// -------------------------------------------------------------------------
#define AB_EXT 391
#define AB_INT 196
#define AB_BAT 13
#define AB_PRE 8

__global__ __launch_bounds__(256) void aux_kernel(
    const int4* __restrict__ ei4, const int4* __restrict__ iei4,
    const int* __restrict__ batch,
    const float* __restrict__ wu_e1, const float* __restrict__ wu_e2,
    const float* __restrict__ wu_i1, const float* __restrict__ wu_i2,
    int* __restrict__ deg_ext, int* __restrict__ deg_int, int* __restrict__ cnt,
    unsigned short* __restrict__ WB, float* __restrict__ wcolp)
{
  __shared__ float WS[64 * 129];
  __shared__ int   hb[64];
  const int b = blockIdx.x, t = threadIdx.x;

  if (b < AB_EXT) {
    const int base = b * 512 + t;
    #pragma unroll
    for (int u = 0; u < 2; ++u) {
      const int i = base + u * 256;
      if (i < NE / 4) {
        const int4 v = ei4[i];
        atomicAdd(&deg_ext[v.x], 1);
        atomicAdd(&deg_ext[v.y], 1);
        atomicAdd(&deg_ext[v.z], 1);
        atomicAdd(&deg_ext[v.w], 1);
      }
    }
  } else if (b < AB_EXT + AB_INT) {
    const int base = (b - AB_EXT) * 512 + t;
    #pragma unroll
    for (int u = 0; u < 2; ++u) {
      const int i = base + u * 256;
      if (i < NEI / 4) {
        const int4 v = iei4[i];
        atomicAdd(&deg_int[v.x], 1);
        atomicAdd(&deg_int[v.y], 1);
        atomicAdd(&deg_int[v.z], 1);
        atomicAdd(&deg_int[v.w], 1);
      }
    }
  } else if (b < AB_EXT + AB_INT + AB_BAT) {
    if (t < 64) hb[t] = 0;
    __syncthreads();
    const int base = (b - AB_EXT - AB_INT) * 4096 + t;
    for (int u = 0; u < 16; ++u) {
      const int i = base + u * 256;
      if (i < NN) atomicAdd(&hb[batch[i]], 1);
    }
    __syncthreads();
    if (t < 64 && hb[t]) atomicAdd(&cnt[t], hb[t]);
  } else {
    const int pb = b - AB_EXT - AB_INT - AB_BAT;   // 0..7
    const int c  = pb >> 1;                         // conv 0..3
    const int h  = pb & 1;                          // row half
    const float* wu = (c == 0) ? wu_e1 : (c == 1) ? wu_e2 : (c == 2) ? wu_i1 : wu_i2;
    for (int idx = t; idx < 64 * 129; idx += 256)
      WS[idx] = wu[(size_t)h * 64 * 129 + idx];
    __syncthreads();
    const int lane = t & 63, u = t >> 6;
    const int n = lane & 15, quad = lane >> 4;
    const int ct = 4 * h + u;
    unsigned short* wb = WB + c * 32768;
    #pragma unroll
    for (int kc = 0; kc < 4; ++kc) {
      const int k0 = kc * 32 + quad * 8;
      const float* src = &WS[(u * 16 + n) * 129 + k0];
      short8 hi, lo;
      #pragma unroll
      for (int e = 0; e < 8; ++e) {
        const float v = src[e];
        const unsigned short hh = bf16h(v);
        hi[e] = (short)hh;
        lo[e] = (short)bf16h(v - bf16tof(hh));
      }
      const int fbase = ((ct * 4 + kc) * 2) * 512 + lane * 8;
      *(short8*)&wb[fbase]       = hi;
      *(short8*)&wb[fbase + 512] = lo;
    }
    if (t < 64) wcolp[c * 128 + h * 64 + t] = WS[t * 129 + 128];
  }
}

// -------------------------------------------------------------------------
// Fused conv chain, split-bf16 MFMA (hi*hi + lo*hi + hi*lo).
// Grid (782, 2): x = 64-node tile, y = chain.  512 threads = 8 waves:
// wave w -> row-tile rt = w>>1 (16 rows), col-half csel = w&1 (4 col-tiles).
// CONV1 A-FRAGMENTS COME DIRECTLY FROM GLOBAL x (no LDS staging, no staging
// barrier): lane(m=lane&15, octet=quad) reads x[row][kc*32+quad*8 .. +8] —
// 16 rows x 128 B contiguous per kc per wave.  csel-partner waves duplicate
// the cheap bf16-split conversion.  LDS holds only E1 (conv2's A).
// Softmax-1 deferred: conv1 writes unnormalized E1 = exp(leaky(.)); conv2
// computes U2 = E1@W2 and s1 = E1@ones via MFMA; logits2 = U2/s1.
// Block barriers: 2 (E1 visibility, s2 reduction) vs R7's 4.
// -------------------------------------------------------------------------
__global__ __launch_bounds__(512, 4) void conv_mfma_kernel(
    const float* __restrict__ x,
    const int* __restrict__ deg_ext, const int* __restrict__ deg_int,
    const int* __restrict__ batch,
    const unsigned short* __restrict__ WB, const float* __restrict__ wcolp,
    const float* __restrict__ bu_e1, const float* __restrict__ bu_e2,
    const float* __restrict__ bu_i1, const float* __restrict__ bu_i2,
    float* __restrict__ ez_sum, float* __restrict__ iz_sum)
{
  __shared__ unsigned short XT[2 * 8192];   // E1 hi/lo fragments, 32 KB
  __shared__ float red[128];                // [row][csel]

  const int tid  = threadIdx.x;
  const int lane = tid & 63;
  const int w    = tid >> 6;
  const int rt   = w >> 1;          // row tile 0..3
  const int csel = w & 1;           // column half 0..1
  const int n    = lane & 15;
  const int q    = lane >> 4;
  const int mbase = blockIdx.x * 64;
  const int chain = blockIdx.y;

  const int*   deg  = chain ? deg_int : deg_ext;
  float*       gsum = chain ? iz_sum : ez_sum;
  const float* buA  = chain ? bu_i1  : bu_e1;
  const float* buB  = chain ? bu_i2  : bu_e2;
  const int conv1 = chain * 2, conv2 = chain * 2 + 1;

  const short8 ONES = {0x3F80, 0x3F80, 0x3F80, 0x3F80, 0x3F80, 0x3F80, 0x3F80, 0x3F80};

#define LOADB(WBP, KC, BH, BL) do {                                          \
    const unsigned short* _p = (WBP) + csel * 16384 + (KC) * 1024 + lane * 8;\
    BH[0] = *(const short8*)&_p[0];     BL[0] = *(const short8*)&_p[512];    \
    BH[1] = *(const short8*)&_p[4096];  BL[1] = *(const short8*)&_p[4608];   \
    BH[2] = *(const short8*)&_p[8192];  BL[2] = *(const short8*)&_p[8704];   \
    BH[3] = *(const short8*)&_p[12288]; BL[3] = *(const short8*)&_p[12800];  \
  } while (0)

  // deg for this wave's 16 rows: lane needs rows quad*4+r
  float dgv[4];
  {
    #pragma unroll
    for (int r = 0; r < 4; ++r) {
      const int node = mbase + rt * 16 + 4 * q + r;
      dgv[r] = (node < NN) ? (float)deg[node] : 0.f;
    }
  }

  // ================= conv1: A direct from global =================
  const unsigned short* wb1 = WB + conv1 * 32768;
  const int arow = mbase + rt * 16 + n;           // this lane's A row
  const bool avalid = (arow < NN);
  const float* xr = x + (size_t)arow * FD + q * 8;

  f32x4 acc[4];
  #pragma unroll
  for (int ct = 0; ct < 4; ++ct) acc[ct] = (f32x4){0.f, 0.f, 0.f, 0.f};

  short8 Bh[4], Bl[4], Bnh[4], Bnl[4];
  LOADB(wb1, 0, Bh, Bl);

  // prefetch kc=0 x
  float4 xa = make_float4(0,0,0,0), xb = xa;
  if (avalid) { xa = *(const float4*)xr; xb = *(const float4*)(xr + 4); }

  #pragma unroll
  for (int kc = 0; kc < 4; ++kc) {
    if (kc < 3) LOADB(wb1, kc + 1, Bnh, Bnl);
    float4 nxa = make_float4(0,0,0,0), nxb = nxa;
    if (kc < 3 && avalid) {
      nxa = *(const float4*)(xr + (kc + 1) * 32);
      nxb = *(const float4*)(xr + (kc + 1) * 32 + 4);
    }
    // convert current x -> Ah/Al
    const float f[8] = {xa.x, xa.y, xa.z, xa.w, xb.x, xb.y, xb.z, xb.w};
    S8 Ah, Al;
    #pragma unroll
    for (int p = 0; p < 4; ++p) {
      const float va = f[2 * p], vb = f[2 * p + 1];
      const unsigned int uh = pk_bf16(va, vb);
      const float la = va - __uint_as_float(uh << 16);
      const float lb = vb - __uint_as_float(uh & 0xFFFF0000u);
      Ah.u[p] = uh;
      Al.u[p] = pk_bf16(la, lb);
    }
    #pragma unroll
    for (int ct = 0; ct < 4; ++ct) {
      f32x4 c = acc[ct];
      c = __builtin_amdgcn_mfma_f32_16x16x32_bf16(Ah.s, Bh[ct], c, 0, 0, 0);
      c = __builtin_amdgcn_mfma_f32_16x16x32_bf16(Al.s, Bh[ct], c, 0, 0, 0);
      c = __builtin_amdgcn_mfma_f32_16x16x32_bf16(Ah.s, Bl[ct], c, 0, 0, 0);
      acc[ct] = c;
    }
    xa = nxa; xb = nxb;
    if (kc < 3) {
      #pragma unroll
      for (int ct = 0; ct < 4; ++ct) { Bh[ct] = Bnh[ct]; Bl[ct] = Bnl[ct]; }
    }
  }

  // ---- epilogue1: E1 = exp(leaky(acc + bias + deg*wcol))  (unnormalized)
  {
    float wc[4], bs[4];
    #pragma unroll
    for (int ct = 0; ct < 4; ++ct) {
      const int j = csel * 64 + ct * 16 + n;
      wc[ct] = wcolp[conv1 * 128 + j];
      bs[ct] = buA[j];
    }
    #pragma unroll
    for (int ct = 0; ct < 4; ++ct)
      #pragma unroll
      for (int r = 0; r < 4; ++r) {
        float v = acc[ct][r] + bs[ct] + dgv[r] * wc[ct];
        v = (v > 0.f) ? v : 0.01f * v;
        acc[ct][r] = __expf(v);
      }
  }

  // ---- write E1 (hi/lo) into XT in A-fragment order:
  // col j = csel*64+ct*16+n -> kc'=csel*2+(ct>>1), qk'=2(ct&1)+(n>>3), e'=n&7
  #pragma unroll
  for (int ct = 0; ct < 4; ++ct) {
    const int kcp = csel * 2 + (ct >> 1);
    const int qkp = ((ct & 1) << 1) + (n >> 3);
    const int ib  = ((rt * 4 + kcp) * 64 + qkp * 16 + 4 * q) * 8 + (n & 7);
    const unsigned int uh01 = pk_bf16(acc[ct][0], acc[ct][1]);
    const unsigned int uh23 = pk_bf16(acc[ct][2], acc[ct][3]);
    const float l0 = acc[ct][0] - __uint_as_float(uh01 << 16);
    const float l1 = acc[ct][1] - __uint_as_float(uh01 & 0xFFFF0000u);
    const float l2 = acc[ct][2] - __uint_as_float(uh23 << 16);
    const float l3 = acc[ct][3] - __uint_as_float(uh23 & 0xFFFF0000u);
    const unsigned int ul01 = pk_bf16(l0, l1);
    const unsigned int ul23 = pk_bf16(l2, l3);
    XT[ib]      = (unsigned short)(uh01 & 0xFFFFu);
    XT[ib + 8]  = (unsigned short)(uh01 >> 16);
    XT[ib + 16] = (unsigned short)(uh23 & 0xFFFFu);
    XT[ib + 24] = (unsigned short)(uh23 >> 16);
    XT[8192 + ib]      = (unsigned short)(ul01 & 0xFFFFu);
    XT[8192 + ib + 8]  = (unsigned short)(ul01 >> 16);
    XT[8192 + ib + 16] = (unsigned short)(ul23 & 0xFFFFu);
    XT[8192 + ib + 24] = (unsigned short)(ul23 >> 16);
  }
  __syncthreads();   // barrier 1: E1 fragments visible to all waves

  // ================= conv2: A from LDS, + s1 via ONES MFMA =================
  const unsigned short* wb2 = WB + conv2 * 32768;
  f32x4 s1a = (f32x4){0.f, 0.f, 0.f, 0.f};
  #pragma unroll
  for (int ct = 0; ct < 4; ++ct) acc[ct] = (f32x4){0.f, 0.f, 0.f, 0.f};

  LOADB(wb2, 0, Bh, Bl);
  #pragma unroll
  for (int kc = 0; kc < 4; ++kc) {
    if (kc < 3) LOADB(wb2, kc + 1, Bnh, Bnl);
    const int ab = ((rt * 4 + kc) * 64 + lane) * 8;
    const short8 Ah = *(const short8*)&XT[ab];
    const short8 Al = *(const short8*)&XT[8192 + ab];
    #pragma unroll
    for (int ct = 0; ct < 4; ++ct) {
      f32x4 c = acc[ct];
      c = __builtin_amdgcn_mfma_f32_16x16x32_bf16(Ah, Bh[ct], c, 0, 0, 0);
      c = __builtin_amdgcn_mfma_f32_16x16x32_bf16(Al, Bh[ct], c, 0, 0, 0);
      c = __builtin_amdgcn_mfma_f32_16x16x32_bf16(Ah, Bl[ct], c, 0, 0, 0);
      acc[ct] = c;
    }
    s1a = __builtin_amdgcn_mfma_f32_16x16x32_bf16(Ah, ONES, s1a, 0, 0, 0);
    s1a = __builtin_amdgcn_mfma_f32_16x16x32_bf16(Al, ONES, s1a, 0, 0, 0);
    if (kc < 3) {
      #pragma unroll
      for (int ct = 0; ct < 4; ++ct) { Bh[ct] = Bnh[ct]; Bl[ct] = Bnl[ct]; }
    }
  }

  // ---- epilogue2: logits2 = U2/s1 + deg*wc + b; E2 = exp(leaky(.)); s2
  {
    float wc[4], bs[4];
    #pragma unroll
    for (int ct = 0; ct < 4; ++ct) {
      const int j = csel * 64 + ct * 16 + n;
      wc[ct] = wcolp[conv2 * 128 + j];
      bs[ct] = buB[j];
    }
    float inv1[4];
    #pragma unroll
    for (int r = 0; r < 4; ++r) inv1[r] = 1.0f / s1a[r];
    #pragma unroll
    for (int ct = 0; ct < 4; ++ct)
      #pragma unroll
      for (int r = 0; r < 4; ++r) {
        float u2 = acc[ct][r] * inv1[r] + bs[ct] + dgv[r] * wc[ct];
        u2 = (u2 > 0.f) ? u2 : 0.01f * u2;
        acc[ct][r] = __expf(u2);
      }
    #pragma unroll
    for (int r = 0; r < 4; ++r) {
      float t = acc[0][r] + acc[1][r] + acc[2][r] + acc[3][r];
      t += __shfl_xor(t, 1);
      t += __shfl_xor(t, 2);
      t += __shfl_xor(t, 4);
      t += __shfl_xor(t, 8);
      if (n == 0) red[(rt * 16 + 4 * q + r) * 2 + csel] = t;
    }
    __syncthreads();   // barrier 2: s2 partials visible
    #pragma unroll
    for (int r = 0; r < 4; ++r) {
      const int row = rt * 16 + 4 * q + r;
      const float inv2 = 1.0f / (red[row * 2] + red[row * 2 + 1]);
      #pragma unroll
      for (int ct = 0; ct < 4; ++ct) acc[ct][r] *= inv2;
    }
  }

  // ---- scatter into per-graph sums (batch sorted: one-graph fast path)
  {
    bool fast = false; int gall = 0;
    if (mbase + 63 < NN) { gall = batch[mbase]; fast = (batch[mbase + 63] == gall); }
    if (fast) {
      #pragma unroll
      for (int ct = 0; ct < 4; ++ct) {
        float s = acc[ct][0] + acc[ct][1] + acc[ct][2] + acc[ct][3];
        s += __shfl_xor(s, 16);
        s += __shfl_xor(s, 32);
        if (q == 0)
          atomicAdd(&gsum[gall * FD + csel * 64 + ct * 16 + n], s);
      }
    } else {
      #pragma unroll
      for (int ct = 0; ct < 4; ++ct) {
        const int j = csel * 64 + ct * 16 + n;
        for (int r = 0; r < 4; ++r) {
          const int node = mbase + rt * 16 + 4 * q + r;
          if (node < NN)
            atomicAdd(&gsum[batch[node] * FD + j], acc[ct][r]);
        }
      }
    }
  }
#undef LOADB
}

// -------------------------------------------------------------------------
// Final MLP: 64 blocks (one per graph) x 128 threads.
// -------------------------------------------------------------------------
__global__ __launch_bounds__(128) void fc_kernel(
    const float* __restrict__ ez_sum, const float* __restrict__ iz_sum,
    const int* __restrict__ cnt,
    const float* __restrict__ fc1_w, const float* __restrict__ fc1_b,
    const float* __restrict__ fc2_w, const float* __restrict__ fc2_b,
    float* __restrict__ out)
{
  __shared__ float z[256];
  __shared__ float red2[2];
  const int g = blockIdx.x, t = threadIdx.x;
  const float denom = fmaxf((float)cnt[g], 1.0f);
  z[t]       = ez_sum[g * 128 + t] / denom;
  z[128 + t] = iz_sum[g * 128 + t] / denom;
  __syncthreads();

  const float* wr = fc1_w + (size_t)t * 256;
  float a = fc1_b[t];
  #pragma unroll 4
  for (int c = 0; c < 256; c += 4) {
    const float4 wv = *(const float4*)(wr + c);
    a += wv.x * z[c] + wv.y * z[c + 1] + wv.z * z[c + 2] + wv.w * z[c + 3];
  }
  a = fmaxf(a, 0.f) * fc2_w[t];
  a += __shfl_xor(a, 1);
  a += __shfl_xor(a, 2);
  a += __shfl_xor(a, 4);
  a += __shfl_xor(a, 8);
  a += __shfl_xor(a, 16);
  a += __shfl_xor(a, 32);
  if ((t & 63) == 0) red2[t >> 6] = a;
  __syncthreads();
  if (t == 0) out[g] = red2[0] + red2[1] + fc2_b[0];
}

// -------------------------------------------------------------------------
extern "C" void kernel_launch(void* const* d_in, const int* in_sizes, int n_in,
                              void* d_out, int out_size, void* d_ws, size_t ws_size,
                              hipStream_t stream) {
  const float* x     = (const float*)d_in[0];
  const int4*  ei4   = (const int4*) d_in[1];   // [2,E]: first E = sources
  const int4*  iei4  = (const int4*) d_in[3];
  const int*   batch = (const int*)  d_in[5];
  const float* wu_e1 = (const float*)d_in[8];
  const float* bu_e1 = (const float*)d_in[9];
  const float* wu_e2 = (const float*)d_in[12];
  const float* bu_e2 = (const float*)d_in[13];
  const float* wu_i1 = (const float*)d_in[16];
  const float* bu_i1 = (const float*)d_in[17];
  const float* wu_i2 = (const float*)d_in[20];
  const float* bu_i2 = (const float*)d_in[21];
  const float* fc1_w = (const float*)d_in[22];
  const float* fc1_b = (const float*)d_in[23];
  const float* fc2_w = (const float*)d_in[24];
  const float* fc2_b = (const float*)d_in[25];

  char* ws = (char*)d_ws;
  int*   deg_ext = (int*)  (ws + DEG_EXT_OFF);
  int*   deg_int = (int*)  (ws + DEG_INT_OFF);
  float* ez      = (float*)(ws + EZ_OFF);
  float* iz      = (float*)(ws + IZ_OFF);
  int*   cnt     = (int*)  (ws + CNT_OFF);
  unsigned short* WB = (unsigned short*)(ws + WB_OFF);
  float* wcolp   = (float*)(ws + WCOL_OFF);

  hipMemsetAsync(d_ws, 0, ZERO_BYTES, stream);

  aux_kernel<<<AB_EXT + AB_INT + AB_BAT + AB_PRE, 256, 0, stream>>>(
      ei4, iei4, batch, wu_e1, wu_e2, wu_i1, wu_i2,
      deg_ext, deg_int, cnt, WB, wcolp);

  conv_mfma_kernel<<<dim3((NN + 63) / 64, 2), 512, 0, stream>>>(
      x, deg_ext, deg_int, batch, WB, wcolp,
      bu_e1, bu_e2, bu_i1, bu_i2, ez, iz);

  fc_kernel<<<NG, 128, 0, stream>>>(ez, iz, cnt, fc1_w, fc1_b, fc2_w, fc2_b,
                                    (float*)d_out);
}

// Round 9
// 240.720 us; speedup vs baseline: 1.0451x; 1.0451x over previous
//
#include <hip/hip_runtime.h>
#include <hip/hip_bf16.h>

// Problem constants
#define NN  50000   // nodes
#define FD  128     // features
#define NE  800000  // external edges
#define NEI 400000  // internal edges
#define NG  64      // graphs

// Workspace layout (bytes). [0, ZERO_BYTES) is zeroed each launch.
#define DEG_EXT_OFF 0        // 50000 int
#define DEG_INT_OFF 200704   // 50000 int
#define EZ_OFF      401408   // 64*128 float
#define IZ_OFF      434176   // 64*128 float
#define CNT_OFF     466944   // 64 int
#define ZERO_BYTES  467200
#define WB_OFF      467200   // 4 convs * 32768 ushort = 256 KB (B fragments)
#define WCOL_OFF    729344   // 4 * 128 float

typedef short  short8 __attribute__((ext_vector_type(8)));
typedef float  f32x4  __attribute__((ext_vector_type(4)));

union S8 { short8 s; unsigned int u[4]; };

__device__ __forceinline__ unsigned short bf16h(float f) {
  unsigned int u = __float_as_uint(f);
  u += 0x7FFFu + ((u >> 16) & 1u);            // RNE
  return (unsigned short)(u >> 16);
}
__device__ __forceinline__ float bf16tof(unsigned short h) {
  return __uint_as_float(((unsigned int)h) << 16);
}
// packed 2xf32 -> 2xbf16 (v_cvt_pk_bf16_f32): a in low 16, b in high 16
__device__ __forceinline__ unsigned int pk_bf16(float a, float b) {
  __hip_bfloat162 h = __float22bfloat162_rn(make_float2(a, b));
  unsigned int u;
  __builtin_memcpy(&u, &h, 4);
  return u;
}

// -------------------------------------------------------------------------
// ONE aux dispatch (unchanged — all pieces measured small):
//  [0,391):    ext edge-degree histogram (softmax([E,1])==1 -> counts)
//  [391,587):  int edge-degree histogram
//  [587,600):  batch histogram (sorted -> LDS-privatized)
//  [600,608):  W -> MFMA B-fragment prep (hi/lo split-bf16), LDS-staged
// -------------------------------------------------------------------------
#define AB_EXT 391
#define AB_INT 196
#define AB_BAT 13
#define AB_PRE 8

__global__ __launch_bounds__(256) void aux_kernel(
    const int4* __restrict__ ei4, const int4* __restrict__ iei4,
    const int* __restrict__ batch,
    const float* __restrict__ wu_e1, const float* __restrict__ wu_e2,
    const float* __restrict__ wu_i1, const float* __restrict__ wu_i2,
    int* __restrict__ deg_ext, int* __restrict__ deg_int, int* __restrict__ cnt,
    unsigned short* __restrict__ WB, float* __restrict__ wcolp)
{
  __shared__ float WS[64 * 129];
  __shared__ int   hb[64];
  const int b = blockIdx.x, t = threadIdx.x;

  if (b < AB_EXT) {
    const int base = b * 512 + t;
    #pragma unroll
    for (int u = 0; u < 2; ++u) {
      const int i = base + u * 256;
      if (i < NE / 4) {
        const int4 v = ei4[i];
        atomicAdd(&deg_ext[v.x], 1);
        atomicAdd(&deg_ext[v.y], 1);
        atomicAdd(&deg_ext[v.z], 1);
        atomicAdd(&deg_ext[v.w], 1);
      }
    }
  } else if (b < AB_EXT + AB_INT) {
    const int base = (b - AB_EXT) * 512 + t;
    #pragma unroll
    for (int u = 0; u < 2; ++u) {
      const int i = base + u * 256;
      if (i < NEI / 4) {
        const int4 v = iei4[i];
        atomicAdd(&deg_int[v.x], 1);
        atomicAdd(&deg_int[v.y], 1);
        atomicAdd(&deg_int[v.z], 1);
        atomicAdd(&deg_int[v.w], 1);
      }
    }
  } else if (b < AB_EXT + AB_INT + AB_BAT) {
    if (t < 64) hb[t] = 0;
    __syncthreads();
    const int base = (b - AB_EXT - AB_INT) * 4096 + t;
    for (int u = 0; u < 16; ++u) {
      const int i = base + u * 256;
      if (i < NN) atomicAdd(&hb[batch[i]], 1);
    }
    __syncthreads();
    if (t < 64 && hb[t]) atomicAdd(&cnt[t], hb[t]);
  } else {
    const int pb = b - AB_EXT - AB_INT - AB_BAT;   // 0..7
    const int c  = pb >> 1;                         // conv 0..3
    const int h  = pb & 1;                          // row half
    const float* wu = (c == 0) ? wu_e1 : (c == 1) ? wu_e2 : (c == 2) ? wu_i1 : wu_i2;
    for (int idx = t; idx < 64 * 129; idx += 256)
      WS[idx] = wu[(size_t)h * 64 * 129 + idx];
    __syncthreads();
    const int lane = t & 63, u = t >> 6;
    const int n = lane & 15, quad = lane >> 4;
    const int ct = 4 * h + u;
    unsigned short* wb = WB + c * 32768;
    #pragma unroll
    for (int kc = 0; kc < 4; ++kc) {
      const int k0 = kc * 32 + quad * 8;
      const float* src = &WS[(u * 16 + n) * 129 + k0];
      short8 hi, lo;
      #pragma unroll
      for (int e = 0; e < 8; ++e) {
        const float v = src[e];
        const unsigned short hh = bf16h(v);
        hi[e] = (short)hh;
        lo[e] = (short)bf16h(v - bf16tof(hh));
      }
      const int fbase = ((ct * 4 + kc) * 2) * 512 + lane * 8;
      *(short8*)&wb[fbase]       = hi;
      *(short8*)&wb[fbase + 512] = lo;
    }
    if (t < 64) wcolp[c * 128 + h * 64 + t] = WS[t * 129 + 128];
  }
}

// -------------------------------------------------------------------------
// Fused conv chain.  A-side in SINGLE bf16 (x and E1; 2^-9 rel error ->
// ~1e-5 final absmax, under 4.2e-5 threshold); W keeps hi/lo 2-term split
// (full weight precision).  Per (kc,ct): 2 MFMA (Ah*Bh + Ah*Bl).
// Grid (782, 2): x = 64-node tile, y = chain.  512 threads = 8 waves:
// wave w -> row-tile rt = w>>1 (16 rows), col-half csel = w&1 (4 col-tiles).
// A staged via LDS (R7 coalescing — R8 proved direct-global is worse).
// Softmax-1 deferred: conv1 writes unnormalized E1 = exp(leaky(.)); conv2
// computes U2 = E1@W2 and s1 = E1@ones via MFMA; logits2 = U2/s1 (s1's
// bf16 error row-uniformly scales U2 -> ~cancels in softmax2).
// LDS: 16.6 KB.  4 barriers.
// -------------------------------------------------------------------------
__global__ __launch_bounds__(512, 4) void conv_mfma_kernel(
    const float* __restrict__ x,
    const int* __restrict__ deg_ext, const int* __restrict__ deg_int,
    const int* __restrict__ batch,
    const unsigned short* __restrict__ WB, const float* __restrict__ wcolp,
    const float* __restrict__ bu_e1, const float* __restrict__ bu_e2,
    const float* __restrict__ bu_i1, const float* __restrict__ bu_i2,
    float* __restrict__ ez_sum, float* __restrict__ iz_sum)
{
  __shared__ unsigned short XT[8192];   // A fragments (bf16), 16 KB
  __shared__ float degs[64];
  __shared__ float red[128];            // [row][csel]

  const int tid  = threadIdx.x;
  const int lane = tid & 63;
  const int w    = tid >> 6;
  const int rt   = w >> 1;          // row tile 0..3
  const int csel = w & 1;           // column half 0..1
  const int n    = lane & 15;
  const int q    = lane >> 4;
  const int mbase = blockIdx.x * 64;
  const int chain = blockIdx.y;

  const int*   deg  = chain ? deg_int : deg_ext;
  float*       gsum = chain ? iz_sum : ez_sum;
  const float* buA  = chain ? bu_i1  : bu_e1;
  const float* buB  = chain ? bu_i2  : bu_e2;
  const int conv1 = chain * 2, conv2 = chain * 2 + 1;

  const short8 ONES = {0x3F80, 0x3F80, 0x3F80, 0x3F80, 0x3F80, 0x3F80, 0x3F80, 0x3F80};

#define LOADB(WBP, KC, BH, BL) do {                                          \
    const unsigned short* _p = (WBP) + csel * 16384 + (KC) * 1024 + lane * 8;\
    BH[0] = *(const short8*)&_p[0];     BL[0] = *(const short8*)&_p[512];    \
    BH[1] = *(const short8*)&_p[4096];  BL[1] = *(const short8*)&_p[4608];   \
    BH[2] = *(const short8*)&_p[8192];  BL[2] = *(const short8*)&_p[8704];   \
    BH[3] = *(const short8*)&_p[12288]; BL[3] = *(const short8*)&_p[12800];  \
  } while (0)

  // ---- stage x -> bf16 A fragments, octet-linear mapping (conflict-free)
  #pragma unroll
  for (int u = 0; u < 2; ++u) {
    const int oct  = u * 512 + tid;          // 1024 octets
    const int frag = oct >> 6, l = oct & 63; // frag = rt_s*4+kc_s, l = qk*16+m
    const int row  = (frag >> 2) * 16 + (l & 15);
    const int k0   = (frag & 3) * 32 + (l >> 4) * 8;
    const int node = mbase + row;
    float4 a = make_float4(0.f, 0.f, 0.f, 0.f), bb = a;
    if (node < NN) {
      const float* xr = x + (size_t)node * FD + k0;
      a  = *(const float4*)xr;
      bb = *(const float4*)(xr + 4);
    }
    S8 hi;
    hi.u[0] = pk_bf16(a.x, a.y);
    hi.u[1] = pk_bf16(a.z, a.w);
    hi.u[2] = pk_bf16(bb.x, bb.y);
    hi.u[3] = pk_bf16(bb.z, bb.w);
    *(short8*)&XT[oct * 8] = hi.s;
  }
  if (tid < 64) {
    const int node = mbase + tid;
    degs[tid] = (node < NN) ? (float)deg[node] : 0.f;
  }
  __syncthreads();   // barrier 1: A fragments + degs visible

  // ================= conv1 =================
  const unsigned short* wb1 = WB + conv1 * 32768;
  f32x4 acc[4];
  #pragma unroll
  for (int ct = 0; ct < 4; ++ct) acc[ct] = (f32x4){0.f, 0.f, 0.f, 0.f};

  short8 Bh[4], Bl[4], Bnh[4], Bnl[4];
  LOADB(wb1, 0, Bh, Bl);

  #pragma unroll
  for (int kc = 0; kc < 4; ++kc) {
    if (kc < 3) LOADB(wb1, kc + 1, Bnh, Bnl);
    const short8 Ah = *(const short8*)&XT[((rt * 4 + kc) * 64 + lane) * 8];
    #pragma unroll
    for (int ct = 0; ct < 4; ++ct) {
      f32x4 c = acc[ct];
      c = __builtin_amdgcn_mfma_f32_16x16x32_bf16(Ah, Bh[ct], c, 0, 0, 0);
      c = __builtin_amdgcn_mfma_f32_16x16x32_bf16(Ah, Bl[ct], c, 0, 0, 0);
      acc[ct] = c;
    }
    if (kc < 3) {
      #pragma unroll
      for (int ct = 0; ct < 4; ++ct) { Bh[ct] = Bnh[ct]; Bl[ct] = Bnl[ct]; }
    }
  }

  const float4 dg = *(const float4*)&degs[rt * 16 + 4 * q];
  const float dgv[4] = {dg.x, dg.y, dg.z, dg.w};

  // ---- epilogue1: E1 = exp(leaky(acc + bias + deg*wcol))  (unnormalized)
  {
    float wc[4], bs[4];
    #pragma unroll
    for (int ct = 0; ct < 4; ++ct) {
      const int j = csel * 64 + ct * 16 + n;
      wc[ct] = wcolp[conv1 * 128 + j];
      bs[ct] = buA[j];
    }
    #pragma unroll
    for (int ct = 0; ct < 4; ++ct)
      #pragma unroll
      for (int r = 0; r < 4; ++r) {
        float v = acc[ct][r] + bs[ct] + dgv[r] * wc[ct];
        v = (v > 0.f) ? v : 0.01f * v;
        acc[ct][r] = __expf(v);
      }
  }
  __syncthreads();   // barrier 2: all conv1 A-reads complete before overwrite

  // ---- write E1 (bf16) into XT in A-fragment order:
  // col j = csel*64+ct*16+n -> kc'=csel*2+(ct>>1), qk'=2(ct&1)+(n>>3), e'=n&7
  #pragma unroll
  for (int ct = 0; ct < 4; ++ct) {
    const int kcp = csel * 2 + (ct >> 1);
    const int qkp = ((ct & 1) << 1) + (n >> 3);
    const int ib  = ((rt * 4 + kcp) * 64 + qkp * 16 + 4 * q) * 8 + (n & 7);
    const unsigned int uh01 = pk_bf16(acc[ct][0], acc[ct][1]);
    const unsigned int uh23 = pk_bf16(acc[ct][2], acc[ct][3]);
    XT[ib]      = (unsigned short)(uh01 & 0xFFFFu);
    XT[ib + 8]  = (unsigned short)(uh01 >> 16);
    XT[ib + 16] = (unsigned short)(uh23 & 0xFFFFu);
    XT[ib + 24] = (unsigned short)(uh23 >> 16);
  }
  __syncthreads();   // barrier 3: E1 fragments visible

  // ================= conv2 (+ s1 via ONES MFMA) =================
  const unsigned short* wb2 = WB + conv2 * 32768;
  f32x4 s1a = (f32x4){0.f, 0.f, 0.f, 0.f};
  #pragma unroll
  for (int ct = 0; ct < 4; ++ct) acc[ct] = (f32x4){0.f, 0.f, 0.f, 0.f};

  LOADB(wb2, 0, Bh, Bl);
  #pragma unroll
  for (int kc = 0; kc < 4; ++kc) {
    if (kc < 3) LOADB(wb2, kc + 1, Bnh, Bnl);
    const short8 Ah = *(const short8*)&XT[((rt * 4 + kc) * 64 + lane) * 8];
    #pragma unroll
    for (int ct = 0; ct < 4; ++ct) {
      f32x4 c = acc[ct];
      c = __builtin_amdgcn_mfma_f32_16x16x32_bf16(Ah, Bh[ct], c, 0, 0, 0);
      c = __builtin_amdgcn_mfma_f32_16x16x32_bf16(Ah, Bl[ct], c, 0, 0, 0);
      acc[ct] = c;
    }
    s1a = __builtin_amdgcn_mfma_f32_16x16x32_bf16(Ah, ONES, s1a, 0, 0, 0);
    if (kc < 3) {
      #pragma unroll
      for (int ct = 0; ct < 4; ++ct) { Bh[ct] = Bnh[ct]; Bl[ct] = Bnl[ct]; }
    }
  }

  // ---- epilogue2: logits2 = U2/s1 + deg*wc + b; E2 = exp(leaky(.)); s2
  {
    float wc[4], bs[4];
    #pragma unroll
    for (int ct = 0; ct < 4; ++ct) {
      const int j = csel * 64 + ct * 16 + n;
      wc[ct] = wcolp[conv2 * 128 + j];
      bs[ct] = buB[j];
    }
    float inv1[4];
    #pragma unroll
    for (int r = 0; r < 4; ++r) inv1[r] = 1.0f / s1a[r];
    #pragma unroll
    for (int ct = 0; ct < 4; ++ct)
      #pragma unroll
      for (int r = 0; r < 4; ++r) {
        float u2 = acc[ct][r] * inv1[r] + bs[ct] + dgv[r] * wc[ct];
        u2 = (u2 > 0.f) ? u2 : 0.01f * u2;
        acc[ct][r] = __expf(u2);
      }
    #pragma unroll
    for (int r = 0; r < 4; ++r) {
      float t = acc[0][r] + acc[1][r] + acc[2][r] + acc[3][r];
      t += __shfl_xor(t, 1);
      t += __shfl_xor(t, 2);
      t += __shfl_xor(t, 4);
      t += __shfl_xor(t, 8);
      if (n == 0) red[(rt * 16 + 4 * q + r) * 2 + csel] = t;
    }
    __syncthreads();   // barrier 4: s2 partials visible
    #pragma unroll
    for (int r = 0; r < 4; ++r) {
      const int row = rt * 16 + 4 * q + r;
      const float inv2 = 1.0f / (red[row * 2] + red[row * 2 + 1]);
      #pragma unroll
      for (int ct = 0; ct < 4; ++ct) acc[ct][r] *= inv2;
    }
  }

  // ---- scatter into per-graph sums (batch sorted: one-graph fast path)
  {
    bool fast = false; int gall = 0;
    if (mbase + 63 < NN) { gall = batch[mbase]; fast = (batch[mbase + 63] == gall); }
    if (fast) {
      #pragma unroll
      for (int ct = 0; ct < 4; ++ct) {
        float s = acc[ct][0] + acc[ct][1] + acc[ct][2] + acc[ct][3];
        s += __shfl_xor(s, 16);
        s += __shfl_xor(s, 32);
        if (q == 0)
          atomicAdd(&gsum[gall * FD + csel * 64 + ct * 16 + n], s);
      }
    } else {
      #pragma unroll
      for (int ct = 0; ct < 4; ++ct) {
        const int j = csel * 64 + ct * 16 + n;
        for (int r = 0; r < 4; ++r) {
          const int node = mbase + rt * 16 + 4 * q + r;
          if (node < NN)
            atomicAdd(&gsum[batch[node] * FD + j], acc[ct][r]);
        }
      }
    }
  }
#undef LOADB
}

// -------------------------------------------------------------------------
// Final MLP: 64 blocks (one per graph) x 128 threads.
// -------------------------------------------------------------------------
__global__ __launch_bounds__(128) void fc_kernel(
    const float* __restrict__ ez_sum, const float* __restrict__ iz_sum,
    const int* __restrict__ cnt,
    const float* __restrict__ fc1_w, const float* __restrict__ fc1_b,
    const float* __restrict__ fc2_w, const float* __restrict__ fc2_b,
    float* __restrict__ out)
{
  __shared__ float z[256];
  __shared__ float red2[2];
  const int g = blockIdx.x, t = threadIdx.x;
  const float denom = fmaxf((float)cnt[g], 1.0f);
  z[t]       = ez_sum[g * 128 + t] / denom;
  z[128 + t] = iz_sum[g * 128 + t] / denom;
  __syncthreads();

  const float* wr = fc1_w + (size_t)t * 256;
  float a = fc1_b[t];
  #pragma unroll 4
  for (int c = 0; c < 256; c += 4) {
    const float4 wv = *(const float4*)(wr + c);
    a += wv.x * z[c] + wv.y * z[c + 1] + wv.z * z[c + 2] + wv.w * z[c + 3];
  }
  a = fmaxf(a, 0.f) * fc2_w[t];
  a += __shfl_xor(a, 1);
  a += __shfl_xor(a, 2);
  a += __shfl_xor(a, 4);
  a += __shfl_xor(a, 8);
  a += __shfl_xor(a, 16);
  a += __shfl_xor(a, 32);
  if ((t & 63) == 0) red2[t >> 6] = a;
  __syncthreads();
  if (t == 0) out[g] = red2[0] + red2[1] + fc2_b[0];
}

// -------------------------------------------------------------------------
extern "C" void kernel_launch(void* const* d_in, const int* in_sizes, int n_in,
                              void* d_out, int out_size, void* d_ws, size_t ws_size,
                              hipStream_t stream) {
  const float* x     = (const float*)d_in[0];
  const int4*  ei4   = (const int4*) d_in[1];   // [2,E]: first E = sources
  const int4*  iei4  = (const int4*) d_in[3];
  const int*   batch = (const int*)  d_in[5];
  const float* wu_e1 = (const float*)d_in[8];
  const float* bu_e1 = (const float*)d_in[9];
  const float* wu_e2 = (const float*)d_in[12];
  const float* bu_e2 = (const float*)d_in[13];
  const float* wu_i1 = (const float*)d_in[16];
  const float* bu_i1 = (const float*)d_in[17];
  const float* wu_i2 = (const float*)d_in[20];
  const float* bu_i2 = (const float*)d_in[21];
  const float* fc1_w = (const float*)d_in[22];
  const float* fc1_b = (const float*)d_in[23];
  const float* fc2_w = (const float*)d_in[24];
  const float* fc2_b = (const float*)d_in[25];

  char* ws = (char*)d_ws;
  int*   deg_ext = (int*)  (ws + DEG_EXT_OFF);
  int*   deg_int = (int*)  (ws + DEG_INT_OFF);
  float* ez      = (float*)(ws + EZ_OFF);
  float* iz      = (float*)(ws + IZ_OFF);
  int*   cnt     = (int*)  (ws + CNT_OFF);
  unsigned short* WB = (unsigned short*)(ws + WB_OFF);
  float* wcolp   = (float*)(ws + WCOL_OFF);

  hipMemsetAsync(d_ws, 0, ZERO_BYTES, stream);

  aux_kernel<<<AB_EXT + AB_INT + AB_BAT + AB_PRE, 256, 0, stream>>>(
      ei4, iei4, batch, wu_e1, wu_e2, wu_i1, wu_i2,
      deg_ext, deg_int, cnt, WB, wcolp);

  conv_mfma_kernel<<<dim3((NN + 63) / 64, 2), 512, 0, stream>>>(
      x, deg_ext, deg_int, batch, WB, wcolp,
      bu_e1, bu_e2, bu_i1, bu_i2, ez, iz);

  fc_kernel<<<NG, 128, 0, stream>>>(ez, iz, cnt, fc1_w, fc1_b, fc2_w, fc2_b,
                                    (float*)d_out);
}